// Round 1
// baseline (467.987 us; speedup 1.0000x reference)
//
#include <hip/hip_runtime.h>
#include <math.h>

#define NB 32
#define NC 192
#define NCR 48
#define NT 16
#define NHW 784
#define NHW4 196   // 784 floats = 196 float4

// Kernel A: spatial mean over H*W for each (b,c,t).
// One wave (64 lanes) per (b,c,t) slab of 784 floats (196 float4).
__global__ __launch_bounds__(256) void spatial_mean_kernel(
    const float* __restrict__ x, float* __restrict__ sq) {
  const int wave = threadIdx.x >> 6;
  const int lane = threadIdx.x & 63;
  const int slab = blockIdx.x * 4 + wave;        // slab = (b*NC + c)*NT + t
  const float4* x4 = (const float4*)x + (size_t)slab * NHW4;

  float s = 0.f;
  float4 v;
  v = x4[lane];        s += v.x + v.y + v.z + v.w;
  v = x4[lane + 64];   s += v.x + v.y + v.z + v.w;
  v = x4[lane + 128];  s += v.x + v.y + v.z + v.w;
  if (lane < 4) { v = x4[lane + 192]; s += v.x + v.y + v.z + v.w; }

  #pragma unroll
  for (int off = 32; off > 0; off >>= 1) s += __shfl_down(s, off);
  if (lane == 0) sq[slab] = s * (1.0f / (float)NHW);
}

// Kernel B: per (b,t): h = relu(w1 @ s + b1); attn = sigmoid(w2 @ h + b2);
// coef[b,c,t] = 0.5*attn + 0.5*ms_weight[t]  (multi-scale folded in).
// One block of 192 threads per (b,t) problem; 512 blocks total (tiny).
__global__ __launch_bounds__(192) void attn_coef_kernel(
    const float* __restrict__ sq, const float* __restrict__ w1,
    const float* __restrict__ b1, const float* __restrict__ w2,
    const float* __restrict__ b2, const float* __restrict__ sw,
    float* __restrict__ coef) {
  __shared__ float s[NC];
  __shared__ float h[NCR];
  const int bt = blockIdx.x;
  const int b = bt >> 4;
  const int t = bt & 15;
  const int tid = threadIdx.x;

  s[tid] = sq[((b * NC + tid) * NT) + t];
  __syncthreads();

  if (tid < NCR) {
    float acc = b1[tid];
    const float* wr = w1 + tid * NC;
    #pragma unroll 8
    for (int c = 0; c < NC; ++c) acc += wr[c] * s[c];
    h[tid] = fmaxf(acc, 0.f);
  }
  __syncthreads();

  float acc = b2[tid];
  const float* wr = w2 + tid * NCR;
  #pragma unroll 8
  for (int o = 0; o < NCR; ++o) acc += wr[o] * h[o];
  const float attn = 1.f / (1.f + expf(-acc));

  // softmax over the 3 scale weights (redundant per-thread; trivial)
  const float s0 = sw[0], s1 = sw[1], s2 = sw[2];
  const float m = fmaxf(s0, fmaxf(s1, s2));
  const float e0 = expf(s0 - m), e1 = expf(s1 - m), e2 = expf(s2 - m);
  const float inv = 1.f / (e0 + e1 + e2);
  float ms = e2 * inv * (1.f / 16.f);            // overall mean term
  if (t >= NT / 2) ms += e1 * inv * (1.f / 8.f); // mid mean term
  if (t == NT - 1) ms += e0 * inv;               // recent term

  coef[(b * NC + tid) * NT + t] = 0.5f * attn + 0.5f * ms;
}

// Kernel C: out[b,c,:,:] = sum_t x[b,c,t,:,:] * coef[b,c,t].
// One block per (b,c) slab; reverse slab order so pass-2 reads the tail of x
// (still resident in the 256 MB L3 after kernel A) first.
__global__ __launch_bounds__(256) void output_kernel(
    const float* __restrict__ x, const float* __restrict__ coef,
    float* __restrict__ out) {
  __shared__ float cf[NT];
  const int slab = (int)gridDim.x - 1 - (int)blockIdx.x;  // slab = b*NC + c
  const int tid = threadIdx.x;

  if (tid < NT) cf[tid] = coef[slab * NT + tid];
  __syncthreads();

  if (tid < NHW4) {
    const float4* x4 = (const float4*)x + (size_t)slab * NT * NHW4 + tid;
    float4 acc = {0.f, 0.f, 0.f, 0.f};
    #pragma unroll
    for (int t = 0; t < NT; ++t) {
      const float4 v = x4[(size_t)t * NHW4];
      const float c = cf[t];
      acc.x += v.x * c; acc.y += v.y * c; acc.z += v.z * c; acc.w += v.w * c;
    }
    ((float4*)out)[(size_t)slab * NHW4 + tid] = acc;
  }
}

extern "C" void kernel_launch(void* const* d_in, const int* in_sizes, int n_in,
                              void* d_out, int out_size, void* d_ws, size_t ws_size,
                              hipStream_t stream) {
  const float* x  = (const float*)d_in[0];
  const float* w1 = (const float*)d_in[1];
  const float* b1 = (const float*)d_in[2];
  const float* w2 = (const float*)d_in[3];
  const float* b2 = (const float*)d_in[4];
  const float* sw = (const float*)d_in[5];
  float* out = (float*)d_out;

  float* sq   = (float*)d_ws;            // NB*NC*NT floats = 384 KiB
  float* coef = sq + NB * NC * NT;       // NB*NC*NT floats = 384 KiB

  // A: 98304 slabs, 4 waves/block -> 24576 blocks
  spatial_mean_kernel<<<NB * NC * NT / 4, 256, 0, stream>>>(x, sq);
  // B: 512 (b,t) problems
  attn_coef_kernel<<<NB * NT, 192, 0, stream>>>(sq, w1, b1, w2, b2, sw, coef);
  // C: 6144 (b,c) slabs
  output_kernel<<<NB * NC, 256, 0, stream>>>(x, coef, out);
}

// Round 3
// 456.015 us; speedup vs baseline: 1.0263x; 1.0263x over previous
//
#include <hip/hip_runtime.h>
#include <math.h>

#define NB 32
#define NC 192
#define NCR 48
#define NT 16
#define NHW 784
#define NHW4 196   // 784 floats = 196 float4

// native clang vector type for nontemporal builtins (HIP_vector_type is a
// struct and is rejected by __builtin_nontemporal_*)
typedef float vfloat4 __attribute__((ext_vector_type(4)));

// Kernel A: spatial mean over H*W for each (b,c,t).
// One wave (64 lanes) per (b,c,t) slab of 784 floats (196 float4).
// Reads are CACHEABLE on purpose: they populate L3 for kernel C's re-read.
__global__ __launch_bounds__(256) void spatial_mean_kernel(
    const float* __restrict__ x, float* __restrict__ sq) {
  const int wave = threadIdx.x >> 6;
  const int lane = threadIdx.x & 63;
  const int slab = blockIdx.x * 4 + wave;        // slab = (b*NC + c)*NT + t
  const float4* x4 = (const float4*)x + (size_t)slab * NHW4;

  float s = 0.f;
  float4 v;
  v = x4[lane];        s += v.x + v.y + v.z + v.w;
  v = x4[lane + 64];   s += v.x + v.y + v.z + v.w;
  v = x4[lane + 128];  s += v.x + v.y + v.z + v.w;
  if (lane < 4) { v = x4[lane + 192]; s += v.x + v.y + v.z + v.w; }

  #pragma unroll
  for (int off = 32; off > 0; off >>= 1) s += __shfl_down(s, off);
  if (lane == 0) sq[slab] = s * (1.0f / (float)NHW);
}

// Kernel B: per (b,t): h = relu(w1 @ s + b1); attn = sigmoid(w2 @ h + b2);
// coef[b,c,t] = 0.5*attn + 0.5*ms_weight[t]  (multi-scale folded in).
// One block of 192 threads per (b,t) problem; 512 blocks total (tiny).
__global__ __launch_bounds__(192) void attn_coef_kernel(
    const float* __restrict__ sq, const float* __restrict__ w1,
    const float* __restrict__ b1, const float* __restrict__ w2,
    const float* __restrict__ b2, const float* __restrict__ sw,
    float* __restrict__ coef) {
  __shared__ float s[NC];
  __shared__ float h[NCR];
  const int bt = blockIdx.x;
  const int b = bt >> 4;
  const int t = bt & 15;
  const int tid = threadIdx.x;

  s[tid] = sq[((b * NC + tid) * NT) + t];
  __syncthreads();

  if (tid < NCR) {
    float acc = b1[tid];
    const float* wr = w1 + tid * NC;
    #pragma unroll 8
    for (int c = 0; c < NC; ++c) acc += wr[c] * s[c];
    h[tid] = fmaxf(acc, 0.f);
  }
  __syncthreads();

  float acc = b2[tid];
  const float* wr = w2 + tid * NCR;
  #pragma unroll 8
  for (int o = 0; o < NCR; ++o) acc += wr[o] * h[o];
  const float attn = 1.f / (1.f + expf(-acc));

  // softmax over the 3 scale weights (redundant per-thread; trivial)
  const float s0 = sw[0], s1 = sw[1], s2 = sw[2];
  const float m = fmaxf(s0, fmaxf(s1, s2));
  const float e0 = expf(s0 - m), e1 = expf(s1 - m), e2 = expf(s2 - m);
  const float inv = 1.f / (e0 + e1 + e2);
  float ms = e2 * inv * (1.f / 16.f);            // overall mean term
  if (t >= NT / 2) ms += e1 * inv * (1.f / 8.f); // mid mean term
  if (t == NT - 1) ms += e0 * inv;               // recent term

  coef[(b * NC + tid) * NT + t] = 0.5f * attn + 0.5f * ms;
}

// Kernel C: out[b,c,:,:] = sum_t x[b,c,t,:,:] * coef[b,c,t].
// One block per (b,c) slab; reverse slab order so pass-2 reads the tail of x
// (still resident in the 256 MB L3 after kernel A) first.
// x reads and out writes are NONTEMPORAL: C is the last consumer of x and the
// only producer of out — don't let them evict A-populated L3 lines that later
// C blocks still need.
__global__ __launch_bounds__(256) void output_kernel(
    const float* __restrict__ x, const float* __restrict__ coef,
    float* __restrict__ out) {
  __shared__ float cf[NT];
  const int slab = (int)gridDim.x - 1 - (int)blockIdx.x;  // slab = b*NC + c
  const int tid = threadIdx.x;

  if (tid < NT) cf[tid] = coef[slab * NT + tid];
  __syncthreads();

  if (tid < NHW4) {
    const vfloat4* x4 = (const vfloat4*)x + (size_t)slab * NT * NHW4 + tid;
    vfloat4 acc = {0.f, 0.f, 0.f, 0.f};
    #pragma unroll
    for (int t = 0; t < NT; ++t) {
      const vfloat4 v = __builtin_nontemporal_load(x4 + (size_t)t * NHW4);
      acc += v * cf[t];
    }
    __builtin_nontemporal_store(acc, (vfloat4*)out + (size_t)slab * NHW4 + tid);
  }
}

extern "C" void kernel_launch(void* const* d_in, const int* in_sizes, int n_in,
                              void* d_out, int out_size, void* d_ws, size_t ws_size,
                              hipStream_t stream) {
  const float* x  = (const float*)d_in[0];
  const float* w1 = (const float*)d_in[1];
  const float* b1 = (const float*)d_in[2];
  const float* w2 = (const float*)d_in[3];
  const float* b2 = (const float*)d_in[4];
  const float* sw = (const float*)d_in[5];
  float* out = (float*)d_out;

  float* sq   = (float*)d_ws;            // NB*NC*NT floats = 384 KiB
  float* coef = sq + NB * NC * NT;       // NB*NC*NT floats = 384 KiB

  // A: 98304 slabs, 4 waves/block -> 24576 blocks
  spatial_mean_kernel<<<NB * NC * NT / 4, 256, 0, stream>>>(x, sq);
  // B: 512 (b,t) problems
  attn_coef_kernel<<<NB * NT, 192, 0, stream>>>(sq, w1, b1, w2, b2, sw, coef);
  // C: 6144 (b,c) slabs
  output_kernel<<<NB * NC, 256, 0, stream>>>(x, coef, out);
}